// Round 9
// baseline (184.775 us; speedup 1.0000x reference)
//
#include <hip/hip_runtime.h>
#include <math.h>

// Problem constants (B,L,H,D) = (2,4096,8,64); sample_k = n_top = 45
#define B_ 2
#define L_ 4096
#define H_ 8
#define D_ 64
#define S_ 45
#define NTOP_ 45
#define SCALE 0.125f  // 1/sqrt(64)
#define TKEYS 64      // keys per attn block
#define NSPLIT 64     // key splits per (b,h)

// ---------------- K1: sparsity measure M = max_s(q.k_s) - sum_s/L ----------------
// One wave per query l, ALL 8 heads at once (index_sample is shared across b,h and
// K[b,idx,:,:] is 2048B contiguous). Lane i: head i/8, dims 8(i%8)..8(i%8)+7.
// Each gather instr reads ONE contiguous 2048B region (1 segment vs 8 before).
// 2-deep software pipeline; sIdx reads are wave-uniform broadcasts (no conflicts).
__global__ __launch_bounds__(256) void compute_M_kernel(
    const float* __restrict__ q, const float* __restrict__ k,
    const int* __restrict__ samp, float* __restrict__ M) {
    __shared__ int sIdx[4 * 48];    // 4 queries x padded 48
    int tid = threadIdx.x;
    int g   = blockIdx.x;           // 0..2047
    int xcd = g & 7;
    int s0  = g >> 3;               // 0..255
    int b   = xcd >> 2;             // XCDs 0-3 -> b=0, 4-7 -> b=1 (K[b]=8MB, L2+L3)
    int chunk = (xcd & 3) + 4 * s0; // 0..1023
    int l0  = chunk * 4;

    if (tid < 4 * S_) {
        int qq = tid / S_, ss = tid - qq * S_;
        sIdx[qq * 48 + ss] = samp[(long)(l0 + qq) * S_ + ss];
    }
    // pad rows: 4 queries x slots {45,46,47} = 12 zero writes (disjoint from staging)
    if (tid < 12) sIdx[(tid / 3) * 48 + S_ + (tid % 3)] = 0;
    __syncthreads();

    int lane = tid & 63, w = tid >> 6;
    int l = l0 + w;
    int h = lane >> 3, part = lane & 7;

    const float4* qrow = (const float4*)(q + ((long)(b * L_ + l)) * (H_ * D_));
    float4 qa = qrow[2 * lane], qb = qrow[2 * lane + 1];

    const float4* kb4 = (const float4*)(k + (long)b * L_ * (H_ * D_));
    const int* myIdx = sIdx + w * 48;

    const float4* r0 = kb4 + (long)myIdx[0] * (H_ * D_ / 4);
    float4 ka0 = r0[2 * lane], kb0 = r0[2 * lane + 1];
    const float4* r1 = kb4 + (long)myIdx[1] * (H_ * D_ / 4);
    float4 ka1 = r1[2 * lane], kb1 = r1[2 * lane + 1];

    float vmax = -INFINITY, vsum = 0.f;
    #pragma unroll 3
    for (int s = 0; s < S_; ++s) {
        int nidx = myIdx[s + 2];    // padded: tail reads row 0, discarded
        const float4* nr = kb4 + (long)nidx * (H_ * D_ / 4);
        float4 na = nr[2 * lane], nb = nr[2 * lane + 1];

        float p = qa.x * ka0.x + qa.y * ka0.y + qa.z * ka0.z + qa.w * ka0.w
                + qb.x * kb0.x + qb.y * kb0.y + qb.z * kb0.z + qb.w * kb0.w;
        p += __shfl_xor(p, 1, 64);
        p += __shfl_xor(p, 2, 64);
        p += __shfl_xor(p, 4, 64);
        vmax = fmaxf(vmax, p);
        vsum += p;

        ka0 = ka1; kb0 = kb1;
        ka1 = na;  kb1 = nb;
    }
    if (part == 0)
        M[((long)(b * H_ + h)) * L_ + l] = vmax - vsum * (1.0f / (float)L_);
}

// ---------------- K2: top-45 set per (b,h) via byte-radix select ----------------
// Output order is arbitrary: reference scatters context_in_q[u] to row M_top[u],
// so only the selected SET matters. Tie-break at threshold = lowest index.
__global__ __launch_bounds__(256) void topk_kernel(
    const float* __restrict__ M, int* __restrict__ topIdx) {
    __shared__ unsigned int hist[256];
    __shared__ unsigned int suf[257];
    __shared__ unsigned int wsum[4];
    __shared__ int sBin, sRemain, sCnt, sTieCnt;
    __shared__ int tie[64];

    int bh = blockIdx.x, tid = threadIdx.x;
    int lane = tid & 63, wave = tid >> 6;
    const float* row = M + (long)bh * L_;

    unsigned int key[16];
    #pragma unroll
    for (int j = 0; j < 16; ++j) {
        unsigned int bts = __float_as_uint(row[tid + 256 * j]);
        key[j] = bts ^ ((unsigned int)((int)bts >> 31) | 0x80000000u);
    }

    unsigned int prefix = 0, pmask = 0;
    int remain = NTOP_;
    #pragma unroll 1
    for (int pass = 3; pass >= 0; --pass) {
        int shift = pass * 8;
        hist[tid] = 0;
        __syncthreads();
        #pragma unroll
        for (int j = 0; j < 16; ++j) {
            if ((key[j] & pmask) == prefix)
                atomicAdd(&hist[(key[j] >> shift) & 255u], 1u);
        }
        __syncthreads();
        // suffix sum suf[t] = sum_{i>=t} hist[i]
        unsigned int s = hist[tid];
        #pragma unroll
        for (int off = 1; off < 64; off <<= 1) {
            unsigned int o = __shfl_down(s, off, 64);
            if (lane + off < 64) s += o;
        }
        if (lane == 0) wsum[wave] = s;
        __syncthreads();
        unsigned int add = 0;
        for (int w = wave + 1; w < 4; ++w) add += wsum[w];
        s += add;
        suf[tid] = s;
        if (tid == 0) suf[256] = 0;
        __syncthreads();
        if (suf[tid] >= (unsigned int)remain && suf[tid + 1] < (unsigned int)remain) {
            sBin = tid;
            sRemain = remain - (int)suf[tid + 1];
        }
        __syncthreads();
        prefix |= ((unsigned int)sBin) << shift;
        pmask  |= 0xFFu << shift;
        remain  = sRemain;
        __syncthreads();
    }

    if (tid == 0) { sCnt = 0; sTieCnt = 0; }
    __syncthreads();
    int* outRow = topIdx + bh * NTOP_;
    #pragma unroll
    for (int j = 0; j < 16; ++j) {
        int idx = tid + 256 * j;
        if (key[j] > prefix) {
            int pos = atomicAdd(&sCnt, 1);
            outRow[pos] = idx;
        } else if (key[j] == prefix) {
            int tp = atomicAdd(&sTieCnt, 1);
            if (tp < 64) tie[tp] = idx;
        }
    }
    __syncthreads();
    if (tid == 0) {
        int base = sCnt;   // == NTOP_ - remain
        int tc = sTieCnt < 64 ? sTieCnt : 64;
        for (int t = 0; t < remain; ++t) {
            int mi = 0x7fffffff, mj = 0;
            for (int j2 = 0; j2 < tc; ++j2)
                if (tie[j2] < mi) { mi = tie[j2]; mj = j2; }
            outRow[base + t] = mi;
            tie[mj] = 0x7fffffff;
        }
    }
}

// ---------------- K3: key-strip attention, all-up-front loads, 2 barriers ----------------
// grid = NSPLIT*16 blocks. Q, K, V loaded into separate LDS buffers in one issue
// burst (one vmcnt drain, one barrier), then S -> barrier -> PV.
#define STRIDE 68     // padded LDS row stride (floats)
__global__ __launch_bounds__(256, 2) void attn_strip_kernel(
    const float* __restrict__ q, const float* __restrict__ k,
    const float* __restrict__ v, const int* __restrict__ topIdx,
    float* __restrict__ pOut, float* __restrict__ plPart, int nsplit) {
    __shared__ float sQ[48 * STRIDE];     // 13.1 KB
    __shared__ float sK[TKEYS * STRIDE];  // 17.4 KB
    __shared__ float sV[TKEYS * STRIDE];  // 17.4 KB
    __shared__ float sP[48 * STRIDE];     // 13.1 KB  (64 keys + pad)

    int g = blockIdx.x;
    int xcd = g & 7;
    int s0 = g >> 3;                  // 0 .. nsplit*2-1
    int grp = s0 / nsplit;            // 0..1
    int bh = xcd + 8 * grp;
    int split = s0 - grp * nsplit;
    int b = bh >> 3, h = bh & 7;
    int tid = threadIdx.x;
    int key0 = split * TKEYS;

    // ---- issue ALL global loads up front ----
    // Q: 48 rows x 16 float4 = 768 -> 3/thread (topIdx read direct, L2-hot)
    #pragma unroll
    for (int j = 0; j < 3; ++j) {
        int i = tid + 256 * j;
        int u = i >> 4, d4 = i & 15;
        float4 val = make_float4(0.f, 0.f, 0.f, 0.f);
        if (u < NTOP_) {
            int lq = topIdx[bh * NTOP_ + u];
            val = *(const float4*)(q + (((long)(b * L_ + lq)) * H_ + h) * D_ + 4 * d4);
        }
        *(float4*)(sQ + u * STRIDE + 4 * d4) = val;
    }
    // K and V: 64 rows x 16 float4 = 1024 each -> 4/thread each
    #pragma unroll
    for (int j = 0; j < 4; ++j) {
        int i = tid + 256 * j;
        int r = i >> 4, d4 = i & 15;
        long off = (((long)(b * L_ + key0 + r)) * H_ + h) * D_ + 4 * d4;
        *(float4*)(sK + r * STRIDE + 4 * d4) = *(const float4*)(k + off);
        *(float4*)(sV + r * STRIDE + 4 * d4) = *(const float4*)(v + off);
    }
    __syncthreads();

    // ---- S phase: thread (ty,tx): u = 3ty+i (i<3) x keys tx+16j (j<4) ----
    int tx = tid & 15, ty = tid >> 4;
    float acc[3][4];
    #pragma unroll
    for (int i = 0; i < 3; ++i)
        #pragma unroll
        for (int j = 0; j < 4; ++j) acc[i][j] = 0.f;

    #pragma unroll 4
    for (int d4 = 0; d4 < 16; ++d4) {
        float4 qv[3];
        #pragma unroll
        for (int i = 0; i < 3; ++i)
            qv[i] = *(const float4*)(sQ + (3 * ty + i) * STRIDE + 4 * d4);
        #pragma unroll
        for (int j = 0; j < 4; ++j) {
            float4 kv = *(const float4*)(sK + (tx + 16 * j) * STRIDE + 4 * d4);
            #pragma unroll
            for (int i = 0; i < 3; ++i)
                acc[i][j] += qv[i].x * kv.x + qv[i].y * kv.y + qv[i].z * kv.z + qv[i].w * kv.w;
        }
    }
    #pragma unroll
    for (int i = 0; i < 3; ++i) {
        #pragma unroll
        for (int j = 0; j < 4; ++j)
            sP[(3 * ty + i) * STRIDE + tx + 16 * j] = __expf(acc[i][j] * SCALE);
    }
    __syncthreads();

    // ---- PV phase: thread (uy,dx): u = 3uy+i (i<3) x d = 4dx..4dx+3 ----
    int dx = tid & 15, uy = tid >> 4;
    float o[3][4];
    float ls[3];
    #pragma unroll
    for (int i = 0; i < 3; ++i) {
        ls[i] = 0.f;
        #pragma unroll
        for (int c = 0; c < 4; ++c) o[i][c] = 0.f;
    }
    #pragma unroll 4
    for (int k4 = 0; k4 < 16; ++k4) {
        float pa[3][4];
        #pragma unroll
        for (int i = 0; i < 3; ++i)
            *(float4*)pa[i] = *(const float4*)(sP + (3 * uy + i) * STRIDE + 4 * k4);
        #pragma unroll
        for (int c = 0; c < 4; ++c) {
            float4 vr = *(const float4*)(sV + (4 * k4 + c) * STRIDE + 4 * dx);
            #pragma unroll
            for (int i = 0; i < 3; ++i) {
                o[i][0] += pa[i][c] * vr.x;
                o[i][1] += pa[i][c] * vr.y;
                o[i][2] += pa[i][c] * vr.z;
                o[i][3] += pa[i][c] * vr.w;
                ls[i]   += pa[i][c];
            }
        }
    }
    // store partials (contention-free)
    #pragma unroll
    for (int i = 0; i < 3; ++i) {
        int u = 3 * uy + i;
        if (u < NTOP_) {
            long base = ((long)(split * 16 + bh) * NTOP_ + u) * D_;
            *(float4*)(pOut + base + 4 * dx) = make_float4(o[i][0], o[i][1], o[i][2], o[i][3]);
            if (dx == 0) plPart[(long)(split * 16 + bh) * NTOP_ + u] = ls[i];
        }
    }
}

// ---------------- K4: reduce partials across splits, normalize, scatter ----------------
__global__ __launch_bounds__(256) void reduce_norm_kernel(
    const int* __restrict__ topIdx, const float* __restrict__ pOut,
    const float* __restrict__ plPart, float* __restrict__ out, int nsplit) {
    __shared__ float part[4][64];
    __shared__ float lpart[4];
    int u = blockIdx.x, bh = blockIdx.y;
    int b = bh >> 3, h = bh & 7;
    int tid = threadIdx.x;
    int d = tid & 63, sg = tid >> 6;
    float acc = 0.f, lsum = 0.f;
    for (int s = sg; s < nsplit; s += 4) {
        acc  += pOut[((long)(s * 16 + bh) * NTOP_ + u) * D_ + d];
        lsum += plPart[(long)(s * 16 + bh) * NTOP_ + u];
    }
    part[sg][d] = acc;
    if (d == 0) lpart[sg] = lsum;
    __syncthreads();
    if (sg == 0) {
        float a = part[0][d] + part[1][d] + part[2][d] + part[3][d];
        float lt = lpart[0] + lpart[1] + lpart[2] + lpart[3];
        int lq = topIdx[bh * NTOP_ + u];
        out[(((long)(b * L_ + lq)) * H_ + h) * D_ + d] = a / lt;
    }
}

extern "C" void kernel_launch(void* const* d_in, const int* in_sizes, int n_in,
                              void* d_out, int out_size, void* d_ws, size_t ws_size,
                              hipStream_t stream) {
    const float* q = (const float*)d_in[0];
    const float* k = (const float*)d_in[1];
    const float* v = (const float*)d_in[2];
    // d_in[3] = attn_mask (unused)
    const int* samp = (const int*)d_in[4];
    float* out = (float*)d_out;

    char* ws = (char*)d_ws;
    const size_t mBytes   = (size_t)B_ * H_ * L_ * sizeof(float);   // 512 KB
    const size_t topBytes = (size_t)B_ * H_ * NTOP_ * sizeof(int);  // 2880 B
    const size_t plBytes  = (size_t)NSPLIT * 16 * NTOP_ * sizeof(float);
    float* M      = (float*)ws;
    int*   topIdx = (int*)(ws + mBytes);
    float* plPart = (float*)(ws + mBytes + topBytes);
    float* pOut   = (float*)(ws + mBytes + topBytes + plBytes);

    // pick split count that fits the workspace
    int nsplit = NSPLIT;
    while (nsplit > 1) {
        size_t need = mBytes + topBytes + plBytes +
                      (size_t)nsplit * 16 * NTOP_ * D_ * sizeof(float);
        if (need <= ws_size) break;
        nsplit >>= 1;
    }

    hipMemsetAsync(d_out, 0, (size_t)out_size * sizeof(float), stream);

    compute_M_kernel<<<2048, 256, 0, stream>>>(q, k, samp, M);

    topk_kernel<<<B_ * H_, 256, 0, stream>>>(M, topIdx);

    attn_strip_kernel<<<nsplit * B_ * H_, 256, 0, stream>>>(
        q, k, v, topIdx, pOut, plPart, nsplit);

    dim3 gn(NTOP_, B_ * H_);
    reduce_norm_kernel<<<gn, 256, 0, stream>>>(topIdx, pOut, plPart, out, nsplit);
}

// Round 10
// 166.309 us; speedup vs baseline: 1.1110x; 1.1110x over previous
//
#include <hip/hip_runtime.h>
#include <math.h>

// Problem constants (B,L,H,D) = (2,4096,8,64); sample_k = n_top = 45
#define B_ 2
#define L_ 4096
#define H_ 8
#define D_ 64
#define S_ 45
#define NTOP_ 45
#define SCALE 0.125f  // 1/sqrt(64)
#define TKEYS 64      // keys per attn block
#define NSPLIT 64     // key splits per (b,h)

// ---------------- K1: sparsity measure M = max_s(q.k_s) - sum_s/L ----------------
// Gather granularity = 2-head slice (512B contiguous). Combo (b, head-pair) -> one
// XCD each: per-XCD K footprint 4096x512B = 2MB, L2-resident (the R9 full-row
// layout was 8MB/XCD -> 50% L2 miss -> 202MB L3 traffic; this restores residency
// while keeping 1-2 contiguous segments per gather instruction).
// Wave: lanes 0-31 query A, 32-63 query B; lane float4 = head (i32>>4), dims 4*(i32&15).
__global__ __launch_bounds__(256) void compute_M_kernel(
    const float* __restrict__ q, const float* __restrict__ k,
    const int* __restrict__ samp, float* __restrict__ M) {
    __shared__ int sIdx[8 * 48];    // 8 queries x padded 48
    int tid = threadIdx.x;
    int g   = blockIdx.x;           // 0..4095
    int xcd = g & 7;
    int blk = g >> 3;               // 0..511
    int b   = xcd >> 2;             // combo: b = xcd/4, head-pair = xcd%4
    int hp  = xcd & 3;
    int l0  = blk * 8;

    for (int i = tid; i < 8 * S_; i += 256) {
        int qq = i / S_, ss = i - qq * S_;
        sIdx[qq * 48 + ss] = samp[(long)(l0 + qq) * S_ + ss];
    }
    // pad rows: 8 queries x slots {45,46,47} = 24 zero writes (disjoint from staging)
    if (tid < 24) sIdx[(tid / 3) * 48 + S_ + (tid % 3)] = 0;
    __syncthreads();

    int lane = tid & 63, w = tid >> 6;
    int qh  = lane >> 5;            // which of the wave's 2 queries
    int i32 = lane & 31;
    int qi  = w * 2 + qh;           // query within block (0..7)
    int l   = l0 + qi;
    int hl  = i32 >> 4;             // head within pair
    int part = i32 & 15;

    const float* qbase = q + ((long)(b * L_ + l)) * (H_ * D_) + hp * 128;
    float4 qf = *(const float4*)(qbase + i32 * 4);

    const float* kbase = k + (long)b * L_ * (H_ * D_) + hp * 128;
    const int* myIdx = sIdx + qi * 48;

    float4 k0 = *(const float4*)(kbase + (long)myIdx[0] * (H_ * D_) + i32 * 4);
    float4 k1 = *(const float4*)(kbase + (long)myIdx[1] * (H_ * D_) + i32 * 4);

    float vmax = -INFINITY, vsum = 0.f;
    #pragma unroll 5
    for (int s = 0; s < S_; ++s) {
        int nidx = myIdx[s + 2];    // padded: tail reads row 0, discarded
        float4 kn = *(const float4*)(kbase + (long)nidx * (H_ * D_) + i32 * 4);

        float p = qf.x * k0.x + qf.y * k0.y + qf.z * k0.z + qf.w * k0.w;
        p += __shfl_xor(p, 1, 64);
        p += __shfl_xor(p, 2, 64);
        p += __shfl_xor(p, 4, 64);
        p += __shfl_xor(p, 8, 64);
        vmax = fmaxf(vmax, p);
        vsum += p;

        k0 = k1; k1 = kn;
    }
    if (part == 0)
        M[((long)(b * H_ + hp * 2 + hl)) * L_ + l] = vmax - vsum * (1.0f / (float)L_);
}

// ---------------- K2: top-45 set per (b,h) via byte-radix select ----------------
// Output order is arbitrary: reference scatters context_in_q[u] to row M_top[u],
// so only the selected SET matters. Tie-break at threshold = lowest index.
__global__ __launch_bounds__(256) void topk_kernel(
    const float* __restrict__ M, int* __restrict__ topIdx) {
    __shared__ unsigned int hist[256];
    __shared__ unsigned int suf[257];
    __shared__ unsigned int wsum[4];
    __shared__ int sBin, sRemain, sCnt, sTieCnt;
    __shared__ int tie[64];

    int bh = blockIdx.x, tid = threadIdx.x;
    int lane = tid & 63, wave = tid >> 6;
    const float* row = M + (long)bh * L_;

    unsigned int key[16];
    #pragma unroll
    for (int j = 0; j < 16; ++j) {
        unsigned int bts = __float_as_uint(row[tid + 256 * j]);
        key[j] = bts ^ ((unsigned int)((int)bts >> 31) | 0x80000000u);
    }

    unsigned int prefix = 0, pmask = 0;
    int remain = NTOP_;
    #pragma unroll 1
    for (int pass = 3; pass >= 0; --pass) {
        int shift = pass * 8;
        hist[tid] = 0;
        __syncthreads();
        #pragma unroll
        for (int j = 0; j < 16; ++j) {
            if ((key[j] & pmask) == prefix)
                atomicAdd(&hist[(key[j] >> shift) & 255u], 1u);
        }
        __syncthreads();
        // suffix sum suf[t] = sum_{i>=t} hist[i]
        unsigned int s = hist[tid];
        #pragma unroll
        for (int off = 1; off < 64; off <<= 1) {
            unsigned int o = __shfl_down(s, off, 64);
            if (lane + off < 64) s += o;
        }
        if (lane == 0) wsum[wave] = s;
        __syncthreads();
        unsigned int add = 0;
        for (int w = wave + 1; w < 4; ++w) add += wsum[w];
        s += add;
        suf[tid] = s;
        if (tid == 0) suf[256] = 0;
        __syncthreads();
        if (suf[tid] >= (unsigned int)remain && suf[tid + 1] < (unsigned int)remain) {
            sBin = tid;
            sRemain = remain - (int)suf[tid + 1];
        }
        __syncthreads();
        prefix |= ((unsigned int)sBin) << shift;
        pmask  |= 0xFFu << shift;
        remain  = sRemain;
        __syncthreads();
    }

    if (tid == 0) { sCnt = 0; sTieCnt = 0; }
    __syncthreads();
    int* outRow = topIdx + bh * NTOP_;
    #pragma unroll
    for (int j = 0; j < 16; ++j) {
        int idx = tid + 256 * j;
        if (key[j] > prefix) {
            int pos = atomicAdd(&sCnt, 1);
            outRow[pos] = idx;
        } else if (key[j] == prefix) {
            int tp = atomicAdd(&sTieCnt, 1);
            if (tp < 64) tie[tp] = idx;
        }
    }
    __syncthreads();
    if (tid == 0) {
        int base = sCnt;   // == NTOP_ - remain
        int tc = sTieCnt < 64 ? sTieCnt : 64;
        for (int t = 0; t < remain; ++t) {
            int mi = 0x7fffffff, mj = 0;
            for (int j2 = 0; j2 < tc; ++j2)
                if (tie[j2] < mi) { mi = tie[j2]; mj = j2; }
            outRow[base + t] = mi;
            tie[mj] = 0x7fffffff;
        }
    }
}

// ---------------- K3: key-strip attention, all-up-front loads, 2 barriers ----------------
// grid = NSPLIT*16 blocks. Q, K, V loaded into separate LDS buffers in one issue
// burst (one vmcnt drain, one barrier), then S -> barrier -> PV.
#define STRIDE 68     // padded LDS row stride (floats)
__global__ __launch_bounds__(256, 2) void attn_strip_kernel(
    const float* __restrict__ q, const float* __restrict__ k,
    const float* __restrict__ v, const int* __restrict__ topIdx,
    float* __restrict__ pOut, float* __restrict__ plPart, int nsplit) {
    __shared__ float sQ[48 * STRIDE];     // 13.1 KB
    __shared__ float sK[TKEYS * STRIDE];  // 17.4 KB
    __shared__ float sV[TKEYS * STRIDE];  // 17.4 KB
    __shared__ float sP[48 * STRIDE];     // 13.1 KB  (64 keys + pad)

    int g = blockIdx.x;
    int xcd = g & 7;
    int s0 = g >> 3;                  // 0 .. nsplit*2-1
    int grp = s0 / nsplit;            // 0..1
    int bh = xcd + 8 * grp;
    int split = s0 - grp * nsplit;
    int b = bh >> 3, h = bh & 7;
    int tid = threadIdx.x;
    int key0 = split * TKEYS;

    // ---- issue ALL global loads up front ----
    // Q: 48 rows x 16 float4 = 768 -> 3/thread (topIdx read direct, L2-hot)
    #pragma unroll
    for (int j = 0; j < 3; ++j) {
        int i = tid + 256 * j;
        int u = i >> 4, d4 = i & 15;
        float4 val = make_float4(0.f, 0.f, 0.f, 0.f);
        if (u < NTOP_) {
            int lq = topIdx[bh * NTOP_ + u];
            val = *(const float4*)(q + (((long)(b * L_ + lq)) * H_ + h) * D_ + 4 * d4);
        }
        *(float4*)(sQ + u * STRIDE + 4 * d4) = val;
    }
    // K and V: 64 rows x 16 float4 = 1024 each -> 4/thread each
    #pragma unroll
    for (int j = 0; j < 4; ++j) {
        int i = tid + 256 * j;
        int r = i >> 4, d4 = i & 15;
        long off = (((long)(b * L_ + key0 + r)) * H_ + h) * D_ + 4 * d4;
        *(float4*)(sK + r * STRIDE + 4 * d4) = *(const float4*)(k + off);
        *(float4*)(sV + r * STRIDE + 4 * d4) = *(const float4*)(v + off);
    }
    __syncthreads();

    // ---- S phase: thread (ty,tx): u = 3ty+i (i<3) x keys tx+16j (j<4) ----
    int tx = tid & 15, ty = tid >> 4;
    float acc[3][4];
    #pragma unroll
    for (int i = 0; i < 3; ++i)
        #pragma unroll
        for (int j = 0; j < 4; ++j) acc[i][j] = 0.f;

    #pragma unroll 4
    for (int d4 = 0; d4 < 16; ++d4) {
        float4 qv[3];
        #pragma unroll
        for (int i = 0; i < 3; ++i)
            qv[i] = *(const float4*)(sQ + (3 * ty + i) * STRIDE + 4 * d4);
        #pragma unroll
        for (int j = 0; j < 4; ++j) {
            float4 kv = *(const float4*)(sK + (tx + 16 * j) * STRIDE + 4 * d4);
            #pragma unroll
            for (int i = 0; i < 3; ++i)
                acc[i][j] += qv[i].x * kv.x + qv[i].y * kv.y + qv[i].z * kv.z + qv[i].w * kv.w;
        }
    }
    #pragma unroll
    for (int i = 0; i < 3; ++i) {
        #pragma unroll
        for (int j = 0; j < 4; ++j)
            sP[(3 * ty + i) * STRIDE + tx + 16 * j] = __expf(acc[i][j] * SCALE);
    }
    __syncthreads();

    // ---- PV phase: thread (uy,dx): u = 3uy+i (i<3) x d = 4dx..4dx+3 ----
    int dx = tid & 15, uy = tid >> 4;
    float o[3][4];
    float ls[3];
    #pragma unroll
    for (int i = 0; i < 3; ++i) {
        ls[i] = 0.f;
        #pragma unroll
        for (int c = 0; c < 4; ++c) o[i][c] = 0.f;
    }
    #pragma unroll 4
    for (int k4 = 0; k4 < 16; ++k4) {
        float pa[3][4];
        #pragma unroll
        for (int i = 0; i < 3; ++i)
            *(float4*)pa[i] = *(const float4*)(sP + (3 * uy + i) * STRIDE + 4 * k4);
        #pragma unroll
        for (int c = 0; c < 4; ++c) {
            float4 vr = *(const float4*)(sV + (4 * k4 + c) * STRIDE + 4 * dx);
            #pragma unroll
            for (int i = 0; i < 3; ++i) {
                o[i][0] += pa[i][c] * vr.x;
                o[i][1] += pa[i][c] * vr.y;
                o[i][2] += pa[i][c] * vr.z;
                o[i][3] += pa[i][c] * vr.w;
                ls[i]   += pa[i][c];
            }
        }
    }
    // store partials (contention-free)
    #pragma unroll
    for (int i = 0; i < 3; ++i) {
        int u = 3 * uy + i;
        if (u < NTOP_) {
            long base = ((long)(split * 16 + bh) * NTOP_ + u) * D_;
            *(float4*)(pOut + base + 4 * dx) = make_float4(o[i][0], o[i][1], o[i][2], o[i][3]);
            if (dx == 0) plPart[(long)(split * 16 + bh) * NTOP_ + u] = ls[i];
        }
    }
}

// ---------------- K4: reduce partials across splits, normalize, scatter ----------------
__global__ __launch_bounds__(256) void reduce_norm_kernel(
    const int* __restrict__ topIdx, const float* __restrict__ pOut,
    const float* __restrict__ plPart, float* __restrict__ out, int nsplit) {
    __shared__ float part[4][64];
    __shared__ float lpart[4];
    int u = blockIdx.x, bh = blockIdx.y;
    int b = bh >> 3, h = bh & 7;
    int tid = threadIdx.x;
    int d = tid & 63, sg = tid >> 6;
    float acc = 0.f, lsum = 0.f;
    for (int s = sg; s < nsplit; s += 4) {
        acc  += pOut[((long)(s * 16 + bh) * NTOP_ + u) * D_ + d];
        lsum += plPart[(long)(s * 16 + bh) * NTOP_ + u];
    }
    part[sg][d] = acc;
    if (d == 0) lpart[sg] = lsum;
    __syncthreads();
    if (sg == 0) {
        float a = part[0][d] + part[1][d] + part[2][d] + part[3][d];
        float lt = lpart[0] + lpart[1] + lpart[2] + lpart[3];
        int lq = topIdx[bh * NTOP_ + u];
        out[(((long)(b * L_ + lq)) * H_ + h) * D_ + d] = a / lt;
    }
}

extern "C" void kernel_launch(void* const* d_in, const int* in_sizes, int n_in,
                              void* d_out, int out_size, void* d_ws, size_t ws_size,
                              hipStream_t stream) {
    const float* q = (const float*)d_in[0];
    const float* k = (const float*)d_in[1];
    const float* v = (const float*)d_in[2];
    // d_in[3] = attn_mask (unused)
    const int* samp = (const int*)d_in[4];
    float* out = (float*)d_out;

    char* ws = (char*)d_ws;
    const size_t mBytes   = (size_t)B_ * H_ * L_ * sizeof(float);   // 512 KB
    const size_t topBytes = (size_t)B_ * H_ * NTOP_ * sizeof(int);  // 2880 B
    const size_t plBytes  = (size_t)NSPLIT * 16 * NTOP_ * sizeof(float);
    float* M      = (float*)ws;
    int*   topIdx = (int*)(ws + mBytes);
    float* plPart = (float*)(ws + mBytes + topBytes);
    float* pOut   = (float*)(ws + mBytes + topBytes + plBytes);

    // pick split count that fits the workspace
    int nsplit = NSPLIT;
    while (nsplit > 1) {
        size_t need = mBytes + topBytes + plBytes +
                      (size_t)nsplit * 16 * NTOP_ * D_ * sizeof(float);
        if (need <= ws_size) break;
        nsplit >>= 1;
    }

    hipMemsetAsync(d_out, 0, (size_t)out_size * sizeof(float), stream);

    compute_M_kernel<<<4096, 256, 0, stream>>>(q, k, samp, M);

    topk_kernel<<<B_ * H_, 256, 0, stream>>>(M, topIdx);

    attn_strip_kernel<<<nsplit * B_ * H_, 256, 0, stream>>>(
        q, k, v, topIdx, pOut, plPart, nsplit);

    dim3 gn(NTOP_, B_ * H_);
    reduce_norm_kernel<<<gn, 256, 0, stream>>>(topIdx, pOut, plPart, out, nsplit);
}

// Round 11
// 164.428 us; speedup vs baseline: 1.1237x; 1.0114x over previous
//
#include <hip/hip_runtime.h>
#include <math.h>

// Problem constants (B,L,H,D) = (2,4096,8,64); sample_k = n_top = 45
#define B_ 2
#define L_ 4096
#define H_ 8
#define D_ 64
#define S_ 45
#define NTOP_ 45
#define SCALE 0.125f  // 1/sqrt(64)
#define TKEYS 32      // keys per attn block
#define NSPLIT 128    // key splits per (b,h)

// ---------------- K1: sparsity measure M = max_s(q.k_s) - sum_s/L ----------------
// R7-winner layout (best measured 43.1us; at the L2 random-gather BW ceiling):
// 8 lanes/query, 8 queries/wave, one (b,h) per block via XCD swizzle (2MB/XCD,
// L2-resident). Lane l8 holds float4s {l8, 8+l8}. 2-deep software pipeline.
// sIdx stride 49 (odd): the 8 distinct per-wave row reads hit 8 distinct banks.
__global__ __launch_bounds__(256) void compute_M_kernel(
    const float* __restrict__ q, const float* __restrict__ k,
    const int* __restrict__ samp, float* __restrict__ M) {
    __shared__ int sIdx[32 * 49];   // 6272 B
    int tid = threadIdx.x;
    int g   = blockIdx.x;           // 0..2047
    int xcd = g & 7;
    int s0  = g >> 3;               // 0..255
    int bh  = xcd + 8 * (s0 >> 7);  // 2 bh per XCD -> K slice stays L2-resident
    int c32 = s0 & 127;             // chunk of 32 queries
    int b = bh >> 3, h = bh & 7;
    int l0 = c32 * 32;

    for (int i = tid; i < 32 * S_; i += 256) {
        int qq = i / S_, ss = i - qq * S_;
        sIdx[qq * 49 + ss] = samp[(long)(l0 + qq) * S_ + ss];
    }
    // pad all 32 rows, slots 45..48 (disjoint from staging writes: ss < 45)
    if (tid < 128) sIdx[(tid >> 2) * 49 + S_ + (tid & 3)] = 0;
    __syncthreads();

    int lane = tid & 63, wave = tid >> 6;
    int l8 = lane & 7;              // cluster lane (0..7)
    int q8 = lane >> 3;             // query within wave (0..7)
    int qi = wave * 8 + q8;         // query within block (0..31)
    int l  = l0 + qi;

    const float4* qrow = (const float4*)(q + (((long)(b * L_ + l)) * H_ + h) * D_);
    float4 qa = qrow[l8], qb = qrow[8 + l8];

    const float4* kb4 = (const float4*)(k + ((long)b * L_ * H_ + h) * (long)D_);
    const int* myIdx = sIdx + qi * 49;

    const float4* r0 = kb4 + (long)myIdx[0] * (H_ * D_ / 4);
    float4 ka0 = r0[l8], kb0 = r0[8 + l8];
    const float4* r1 = kb4 + (long)myIdx[1] * (H_ * D_ / 4);
    float4 ka1 = r1[l8], kb1 = r1[8 + l8];

    float vmax = -INFINITY, vsum = 0.f;
    #pragma unroll 3
    for (int s = 0; s < S_; ++s) {
        int nidx = myIdx[s + 2];    // padded: tail reads row 0, discarded
        const float4* nr = kb4 + (long)nidx * (H_ * D_ / 4);
        float4 na = nr[l8], nb = nr[8 + l8];

        float p = qa.x * ka0.x + qa.y * ka0.y + qa.z * ka0.z + qa.w * ka0.w
                + qb.x * kb0.x + qb.y * kb0.y + qb.z * kb0.z + qb.w * kb0.w;
        p += __shfl_xor(p, 1, 64);
        p += __shfl_xor(p, 2, 64);
        p += __shfl_xor(p, 4, 64);
        vmax = fmaxf(vmax, p);
        vsum += p;

        ka0 = ka1; kb0 = kb1;
        ka1 = na;  kb1 = nb;
    }
    if (l8 == 0)
        M[(long)bh * L_ + l] = vmax - vsum * (1.0f / (float)L_);
}

// ---------------- K2: top-45 set per (b,h) via byte-radix select ----------------
// Output order is arbitrary: reference scatters context_in_q[u] to row M_top[u],
// so only the selected SET matters. Tie-break at threshold = lowest index.
__global__ __launch_bounds__(256) void topk_kernel(
    const float* __restrict__ M, int* __restrict__ topIdx) {
    __shared__ unsigned int hist[256];
    __shared__ unsigned int suf[257];
    __shared__ unsigned int wsum[4];
    __shared__ int sBin, sRemain, sCnt, sTieCnt;
    __shared__ int tie[64];

    int bh = blockIdx.x, tid = threadIdx.x;
    int lane = tid & 63, wave = tid >> 6;
    const float* row = M + (long)bh * L_;

    unsigned int key[16];
    #pragma unroll
    for (int j = 0; j < 16; ++j) {
        unsigned int bts = __float_as_uint(row[tid + 256 * j]);
        key[j] = bts ^ ((unsigned int)((int)bts >> 31) | 0x80000000u);
    }

    unsigned int prefix = 0, pmask = 0;
    int remain = NTOP_;
    #pragma unroll 1
    for (int pass = 3; pass >= 0; --pass) {
        int shift = pass * 8;
        hist[tid] = 0;
        __syncthreads();
        #pragma unroll
        for (int j = 0; j < 16; ++j) {
            if ((key[j] & pmask) == prefix)
                atomicAdd(&hist[(key[j] >> shift) & 255u], 1u);
        }
        __syncthreads();
        // suffix sum suf[t] = sum_{i>=t} hist[i]
        unsigned int s = hist[tid];
        #pragma unroll
        for (int off = 1; off < 64; off <<= 1) {
            unsigned int o = __shfl_down(s, off, 64);
            if (lane + off < 64) s += o;
        }
        if (lane == 0) wsum[wave] = s;
        __syncthreads();
        unsigned int add = 0;
        for (int w = wave + 1; w < 4; ++w) add += wsum[w];
        s += add;
        suf[tid] = s;
        if (tid == 0) suf[256] = 0;
        __syncthreads();
        if (suf[tid] >= (unsigned int)remain && suf[tid + 1] < (unsigned int)remain) {
            sBin = tid;
            sRemain = remain - (int)suf[tid + 1];
        }
        __syncthreads();
        prefix |= ((unsigned int)sBin) << shift;
        pmask  |= 0xFFu << shift;
        remain  = sRemain;
        __syncthreads();
    }

    if (tid == 0) { sCnt = 0; sTieCnt = 0; }
    __syncthreads();
    int* outRow = topIdx + bh * NTOP_;
    #pragma unroll
    for (int j = 0; j < 16; ++j) {
        int idx = tid + 256 * j;
        if (key[j] > prefix) {
            int pos = atomicAdd(&sCnt, 1);
            outRow[pos] = idx;
        } else if (key[j] == prefix) {
            int tp = atomicAdd(&sTieCnt, 1);
            if (tp < 64) tie[tp] = idx;
        }
    }
    __syncthreads();
    if (tid == 0) {
        int base = sCnt;   // == NTOP_ - remain
        int tc = sTieCnt < 64 ? sTieCnt : 64;
        for (int t = 0; t < remain; ++t) {
            int mi = 0x7fffffff, mj = 0;
            for (int j2 = 0; j2 < tc; ++j2)
                if (tie[j2] < mi) { mi = tie[j2]; mj = j2; }
            outRow[base + t] = mi;
            tie[mj] = 0x7fffffff;
        }
    }
}

// ---------------- K3: key-strip attention, all-up-front loads, 2 barriers ----------------
// grid = NSPLIT*16 blocks, 32 keys each. LDS 37.4KB -> 4 blocks/CU (2x R10).
// Q, K, V loaded in one issue burst (one vmcnt drain, one barrier), S -> bar -> PV.
#define STRIDE 68     // padded LDS row stride for Q/K/V (floats)
#define PSTR 36       // padded LDS row stride for P (32 keys + 4)
__global__ __launch_bounds__(256) void attn_strip_kernel(
    const float* __restrict__ q, const float* __restrict__ k,
    const float* __restrict__ v, const int* __restrict__ topIdx,
    float* __restrict__ pOut, float* __restrict__ plPart, int nsplit) {
    __shared__ float sQ[48 * STRIDE];     // 13.1 KB
    __shared__ float sK[TKEYS * STRIDE];  //  8.7 KB
    __shared__ float sV[TKEYS * STRIDE];  //  8.7 KB
    __shared__ float sP[48 * PSTR];       //  6.9 KB

    int g = blockIdx.x;
    int xcd = g & 7;
    int s0 = g >> 3;                  // 0 .. nsplit*2-1
    int grp = s0 / nsplit;            // 0..1
    int bh = xcd + 8 * grp;
    int split = s0 - grp * nsplit;
    int b = bh >> 3, h = bh & 7;
    int tid = threadIdx.x;
    int key0 = split * TKEYS;

    // ---- issue ALL global loads up front ----
    // Q: 48 rows x 16 float4 = 768 -> 3/thread (topIdx read direct, L2-hot)
    #pragma unroll
    for (int j = 0; j < 3; ++j) {
        int i = tid + 256 * j;
        int u = i >> 4, d4 = i & 15;
        float4 val = make_float4(0.f, 0.f, 0.f, 0.f);
        if (u < NTOP_) {
            int lq = topIdx[bh * NTOP_ + u];
            val = *(const float4*)(q + (((long)(b * L_ + lq)) * H_ + h) * D_ + 4 * d4);
        }
        *(float4*)(sQ + u * STRIDE + 4 * d4) = val;
    }
    // K and V: 32 rows x 16 float4 = 512 each -> 2/thread each
    #pragma unroll
    for (int j = 0; j < 2; ++j) {
        int i = tid + 256 * j;
        int r = i >> 4, d4 = i & 15;
        long off = (((long)(b * L_ + key0 + r)) * H_ + h) * D_ + 4 * d4;
        *(float4*)(sK + r * STRIDE + 4 * d4) = *(const float4*)(k + off);
        *(float4*)(sV + r * STRIDE + 4 * d4) = *(const float4*)(v + off);
    }
    __syncthreads();

    // ---- S phase: thread (ty,tx): u = 3ty+i (i<3) x keys tx+16j (j<2) ----
    int tx = tid & 15, ty = tid >> 4;
    float acc[3][2];
    #pragma unroll
    for (int i = 0; i < 3; ++i)
        #pragma unroll
        for (int j = 0; j < 2; ++j) acc[i][j] = 0.f;

    #pragma unroll 4
    for (int d4 = 0; d4 < 16; ++d4) {
        float4 qv[3];
        #pragma unroll
        for (int i = 0; i < 3; ++i)
            qv[i] = *(const float4*)(sQ + (3 * ty + i) * STRIDE + 4 * d4);
        #pragma unroll
        for (int j = 0; j < 2; ++j) {
            float4 kv = *(const float4*)(sK + (tx + 16 * j) * STRIDE + 4 * d4);
            #pragma unroll
            for (int i = 0; i < 3; ++i)
                acc[i][j] += qv[i].x * kv.x + qv[i].y * kv.y + qv[i].z * kv.z + qv[i].w * kv.w;
        }
    }
    #pragma unroll
    for (int i = 0; i < 3; ++i) {
        #pragma unroll
        for (int j = 0; j < 2; ++j)
            sP[(3 * ty + i) * PSTR + tx + 16 * j] = __expf(acc[i][j] * SCALE);
    }
    __syncthreads();

    // ---- PV phase: thread (uy,dx): u = 3uy+i (i<3) x d = 4dx..4dx+3 ----
    int dx = tid & 15, uy = tid >> 4;
    float o[3][4];
    float ls[3];
    #pragma unroll
    for (int i = 0; i < 3; ++i) {
        ls[i] = 0.f;
        #pragma unroll
        for (int c = 0; c < 4; ++c) o[i][c] = 0.f;
    }
    #pragma unroll 4
    for (int k4 = 0; k4 < 8; ++k4) {
        float pa[3][4];
        #pragma unroll
        for (int i = 0; i < 3; ++i)
            *(float4*)pa[i] = *(const float4*)(sP + (3 * uy + i) * PSTR + 4 * k4);
        #pragma unroll
        for (int c = 0; c < 4; ++c) {
            float4 vr = *(const float4*)(sV + (4 * k4 + c) * STRIDE + 4 * dx);
            #pragma unroll
            for (int i = 0; i < 3; ++i) {
                o[i][0] += pa[i][c] * vr.x;
                o[i][1] += pa[i][c] * vr.y;
                o[i][2] += pa[i][c] * vr.z;
                o[i][3] += pa[i][c] * vr.w;
                ls[i]   += pa[i][c];
            }
        }
    }
    // store partials (contention-free)
    #pragma unroll
    for (int i = 0; i < 3; ++i) {
        int u = 3 * uy + i;
        if (u < NTOP_) {
            long base = ((long)(split * 16 + bh) * NTOP_ + u) * D_;
            *(float4*)(pOut + base + 4 * dx) = make_float4(o[i][0], o[i][1], o[i][2], o[i][3]);
            if (dx == 0) plPart[(long)(split * 16 + bh) * NTOP_ + u] = ls[i];
        }
    }
}

// ---------------- K4: reduce partials across splits, normalize, scatter ----------------
__global__ __launch_bounds__(256) void reduce_norm_kernel(
    const int* __restrict__ topIdx, const float* __restrict__ pOut,
    const float* __restrict__ plPart, float* __restrict__ out, int nsplit) {
    __shared__ float part[4][64];
    __shared__ float lpart[4];
    int u = blockIdx.x, bh = blockIdx.y;
    int b = bh >> 3, h = bh & 7;
    int tid = threadIdx.x;
    int d = tid & 63, sg = tid >> 6;
    float acc = 0.f, lsum = 0.f;
    for (int s = sg; s < nsplit; s += 4) {
        acc  += pOut[((long)(s * 16 + bh) * NTOP_ + u) * D_ + d];
        lsum += plPart[(long)(s * 16 + bh) * NTOP_ + u];
    }
    part[sg][d] = acc;
    if (d == 0) lpart[sg] = lsum;
    __syncthreads();
    if (sg == 0) {
        float a = part[0][d] + part[1][d] + part[2][d] + part[3][d];
        float lt = lpart[0] + lpart[1] + lpart[2] + lpart[3];
        int lq = topIdx[bh * NTOP_ + u];
        out[(((long)(b * L_ + lq)) * H_ + h) * D_ + d] = a / lt;
    }
}

extern "C" void kernel_launch(void* const* d_in, const int* in_sizes, int n_in,
                              void* d_out, int out_size, void* d_ws, size_t ws_size,
                              hipStream_t stream) {
    const float* q = (const float*)d_in[0];
    const float* k = (const float*)d_in[1];
    const float* v = (const float*)d_in[2];
    // d_in[3] = attn_mask (unused)
    const int* samp = (const int*)d_in[4];
    float* out = (float*)d_out;

    char* ws = (char*)d_ws;
    const size_t mBytes   = (size_t)B_ * H_ * L_ * sizeof(float);   // 512 KB
    const size_t topBytes = (size_t)B_ * H_ * NTOP_ * sizeof(int);  // 2880 B
    const size_t plBytes  = (size_t)NSPLIT * 16 * NTOP_ * sizeof(float);
    float* M      = (float*)ws;
    int*   topIdx = (int*)(ws + mBytes);
    float* plPart = (float*)(ws + mBytes + topBytes);
    float* pOut   = (float*)(ws + mBytes + topBytes + plBytes);

    // pick split count that fits the workspace
    int nsplit = NSPLIT;
    while (nsplit > 1) {
        size_t need = mBytes + topBytes + plBytes +
                      (size_t)nsplit * 16 * NTOP_ * D_ * sizeof(float);
        if (need <= ws_size) break;
        nsplit >>= 1;
    }

    hipMemsetAsync(d_out, 0, (size_t)out_size * sizeof(float), stream);

    compute_M_kernel<<<2048, 256, 0, stream>>>(q, k, samp, M);

    topk_kernel<<<B_ * H_, 256, 0, stream>>>(M, topIdx);

    attn_strip_kernel<<<nsplit * B_ * H_, 256, 0, stream>>>(
        q, k, v, topIdx, pOut, plPart, nsplit);

    dim3 gn(NTOP_, B_ * H_);
    reduce_norm_kernel<<<gn, 256, 0, stream>>>(topIdx, pOut, plPart, out, nsplit);
}

// Round 12
// 158.166 us; speedup vs baseline: 1.1682x; 1.0396x over previous
//
#include <hip/hip_runtime.h>
#include <math.h>

// Problem constants (B,L,H,D) = (2,4096,8,64); sample_k = n_top = 45
#define B_ 2
#define L_ 4096
#define H_ 8
#define D_ 64
#define S_ 45
#define NTOP_ 45
#define SCALE 0.125f  // 1/sqrt(64)
#define TKEYS 64      // keys per attn block
#define NSPLIT 64     // key splits per (b,h)

// ---------------- K1: sparsity measure M = max_s(q.k_s) - sum_s/L ----------------
// At the L2 random-gather line-rate ceiling (43us across 4 distinct layouts:
// 46K lines/CU at ~0.45 lines/cyc). Layout: 8 lanes/query, 8 queries/wave, one
// (b,h) per block via XCD swizzle (2MB/XCD, L2-resident); lane l8 holds float4s
// {l8, 8+l8}. Depth-3 prefetch (6 loads in flight/lane). sIdx stride 49 (odd).
__global__ __launch_bounds__(256) void compute_M_kernel(
    const float* __restrict__ q, const float* __restrict__ k,
    const int* __restrict__ samp, float* __restrict__ M) {
    __shared__ int sIdx[32 * 49];   // 6272 B
    int tid = threadIdx.x;
    int g   = blockIdx.x;           // 0..2047
    int xcd = g & 7;
    int s0  = g >> 3;               // 0..255
    int bh  = xcd + 8 * (s0 >> 7);  // 2 bh per XCD -> K slice stays L2-resident
    int c32 = s0 & 127;             // chunk of 32 queries
    int b = bh >> 3, h = bh & 7;
    int l0 = c32 * 32;

    for (int i = tid; i < 32 * S_; i += 256) {
        int qq = i / S_, ss = i - qq * S_;
        sIdx[qq * 49 + ss] = samp[(long)(l0 + qq) * S_ + ss];
    }
    // pad all 32 rows, slots 45..48 (disjoint from staging writes: ss < 45)
    if (tid < 128) sIdx[(tid >> 2) * 49 + S_ + (tid & 3)] = 0;
    __syncthreads();

    int lane = tid & 63, wave = tid >> 6;
    int l8 = lane & 7;              // cluster lane (0..7)
    int q8 = lane >> 3;             // query within wave (0..7)
    int qi = wave * 8 + q8;         // query within block (0..31)
    int l  = l0 + qi;

    const float4* qrow = (const float4*)(q + (((long)(b * L_ + l)) * H_ + h) * D_);
    float4 qa = qrow[l8], qb = qrow[8 + l8];

    const float4* kb4 = (const float4*)(k + ((long)b * L_ * H_ + h) * (long)D_);
    const int* myIdx = sIdx + qi * 49;

    const float4* r0 = kb4 + (long)myIdx[0] * (H_ * D_ / 4);
    float4 a0 = r0[l8], b0 = r0[8 + l8];
    const float4* r1 = kb4 + (long)myIdx[1] * (H_ * D_ / 4);
    float4 a1 = r1[l8], b1 = r1[8 + l8];
    const float4* r2 = kb4 + (long)myIdx[2] * (H_ * D_ / 4);
    float4 a2 = r2[l8], b2 = r2[8 + l8];

    float vmax = -INFINITY, vsum = 0.f;
    #pragma unroll 3
    for (int s = 0; s < S_; ++s) {
        int nidx = myIdx[s + 3];    // padded: tail reads row 0, discarded
        const float4* nr = kb4 + (long)nidx * (H_ * D_ / 4);
        float4 na = nr[l8], nb = nr[8 + l8];

        float p = qa.x * a0.x + qa.y * a0.y + qa.z * a0.z + qa.w * a0.w
                + qb.x * b0.x + qb.y * b0.y + qb.z * b0.z + qb.w * b0.w;
        p += __shfl_xor(p, 1, 64);
        p += __shfl_xor(p, 2, 64);
        p += __shfl_xor(p, 4, 64);
        vmax = fmaxf(vmax, p);
        vsum += p;

        a0 = a1; b0 = b1;
        a1 = a2; b1 = b2;
        a2 = na; b2 = nb;
    }
    if (l8 == 0)
        M[(long)bh * L_ + l] = vmax - vsum * (1.0f / (float)L_);
}

// ---------------- K2: top-45 set per (b,h) via byte-radix select ----------------
// Output order is arbitrary: reference scatters context_in_q[u] to row M_top[u],
// so only the selected SET matters. Tie-break at threshold = lowest index.
__global__ __launch_bounds__(256) void topk_kernel(
    const float* __restrict__ M, int* __restrict__ topIdx) {
    __shared__ unsigned int hist[256];
    __shared__ unsigned int suf[257];
    __shared__ unsigned int wsum[4];
    __shared__ int sBin, sRemain, sCnt, sTieCnt;
    __shared__ int tie[64];

    int bh = blockIdx.x, tid = threadIdx.x;
    int lane = tid & 63, wave = tid >> 6;
    const float* row = M + (long)bh * L_;

    unsigned int key[16];
    #pragma unroll
    for (int j = 0; j < 16; ++j) {
        unsigned int bts = __float_as_uint(row[tid + 256 * j]);
        key[j] = bts ^ ((unsigned int)((int)bts >> 31) | 0x80000000u);
    }

    unsigned int prefix = 0, pmask = 0;
    int remain = NTOP_;
    #pragma unroll 1
    for (int pass = 3; pass >= 0; --pass) {
        int shift = pass * 8;
        hist[tid] = 0;
        __syncthreads();
        #pragma unroll
        for (int j = 0; j < 16; ++j) {
            if ((key[j] & pmask) == prefix)
                atomicAdd(&hist[(key[j] >> shift) & 255u], 1u);
        }
        __syncthreads();
        // suffix sum suf[t] = sum_{i>=t} hist[i]
        unsigned int s = hist[tid];
        #pragma unroll
        for (int off = 1; off < 64; off <<= 1) {
            unsigned int o = __shfl_down(s, off, 64);
            if (lane + off < 64) s += o;
        }
        if (lane == 0) wsum[wave] = s;
        __syncthreads();
        unsigned int add = 0;
        for (int w = wave + 1; w < 4; ++w) add += wsum[w];
        s += add;
        suf[tid] = s;
        if (tid == 0) suf[256] = 0;
        __syncthreads();
        if (suf[tid] >= (unsigned int)remain && suf[tid + 1] < (unsigned int)remain) {
            sBin = tid;
            sRemain = remain - (int)suf[tid + 1];
        }
        __syncthreads();
        prefix |= ((unsigned int)sBin) << shift;
        pmask  |= 0xFFu << shift;
        remain  = sRemain;
        __syncthreads();
    }

    if (tid == 0) { sCnt = 0; sTieCnt = 0; }
    __syncthreads();
    int* outRow = topIdx + bh * NTOP_;
    #pragma unroll
    for (int j = 0; j < 16; ++j) {
        int idx = tid + 256 * j;
        if (key[j] > prefix) {
            int pos = atomicAdd(&sCnt, 1);
            outRow[pos] = idx;
        } else if (key[j] == prefix) {
            int tp = atomicAdd(&sTieCnt, 1);
            if (tp < 64) tie[tp] = idx;
        }
    }
    __syncthreads();
    if (tid == 0) {
        int base = sCnt;   // == NTOP_ - remain
        int tc = sTieCnt < 64 ? sTieCnt : 64;
        for (int t = 0; t < remain; ++t) {
            int mi = 0x7fffffff, mj = 0;
            for (int j2 = 0; j2 < tc; ++j2)
                if (tie[j2] < mi) { mi = tie[j2]; mj = j2; }
            outRow[base + t] = mi;
            tie[mj] = 0x7fffffff;
        }
    }
}

// ---------------- K3: key-strip attention, all-up-front loads, 2 barriers ----------------
// grid = NSPLIT*16 blocks (R7 config: best measured). Q, K, V loaded into separate
// LDS buffers in one issue burst (one vmcnt drain, one barrier), then S -> bar -> PV.
#define STRIDE 68     // padded LDS row stride (floats)
__global__ __launch_bounds__(256, 2) void attn_strip_kernel(
    const float* __restrict__ q, const float* __restrict__ k,
    const float* __restrict__ v, const int* __restrict__ topIdx,
    float* __restrict__ pOut, float* __restrict__ plPart, int nsplit) {
    __shared__ float sQ[48 * STRIDE];     // 13.1 KB
    __shared__ float sK[TKEYS * STRIDE];  // 17.4 KB
    __shared__ float sV[TKEYS * STRIDE];  // 17.4 KB
    __shared__ float sP[48 * STRIDE];     // 13.1 KB  (64 keys + pad)

    int g = blockIdx.x;
    int xcd = g & 7;
    int s0 = g >> 3;                  // 0 .. nsplit*2-1
    int grp = s0 / nsplit;            // 0..1
    int bh = xcd + 8 * grp;
    int split = s0 - grp * nsplit;
    int b = bh >> 3, h = bh & 7;
    int tid = threadIdx.x;
    int key0 = split * TKEYS;

    // ---- issue ALL global loads up front ----
    // Q: 48 rows x 16 float4 = 768 -> 3/thread (topIdx read direct, L2-hot)
    #pragma unroll
    for (int j = 0; j < 3; ++j) {
        int i = tid + 256 * j;
        int u = i >> 4, d4 = i & 15;
        float4 val = make_float4(0.f, 0.f, 0.f, 0.f);
        if (u < NTOP_) {
            int lq = topIdx[bh * NTOP_ + u];
            val = *(const float4*)(q + (((long)(b * L_ + lq)) * H_ + h) * D_ + 4 * d4);
        }
        *(float4*)(sQ + u * STRIDE + 4 * d4) = val;
    }
    // K and V: 64 rows x 16 float4 = 1024 each -> 4/thread each
    #pragma unroll
    for (int j = 0; j < 4; ++j) {
        int i = tid + 256 * j;
        int r = i >> 4, d4 = i & 15;
        long off = (((long)(b * L_ + key0 + r)) * H_ + h) * D_ + 4 * d4;
        *(float4*)(sK + r * STRIDE + 4 * d4) = *(const float4*)(k + off);
        *(float4*)(sV + r * STRIDE + 4 * d4) = *(const float4*)(v + off);
    }
    __syncthreads();

    // ---- S phase: thread (ty,tx): u = 3ty+i (i<3) x keys tx+16j (j<4) ----
    int tx = tid & 15, ty = tid >> 4;
    float acc[3][4];
    #pragma unroll
    for (int i = 0; i < 3; ++i)
        #pragma unroll
        for (int j = 0; j < 4; ++j) acc[i][j] = 0.f;

    #pragma unroll 4
    for (int d4 = 0; d4 < 16; ++d4) {
        float4 qv[3];
        #pragma unroll
        for (int i = 0; i < 3; ++i)
            qv[i] = *(const float4*)(sQ + (3 * ty + i) * STRIDE + 4 * d4);
        #pragma unroll
        for (int j = 0; j < 4; ++j) {
            float4 kv = *(const float4*)(sK + (tx + 16 * j) * STRIDE + 4 * d4);
            #pragma unroll
            for (int i = 0; i < 3; ++i)
                acc[i][j] += qv[i].x * kv.x + qv[i].y * kv.y + qv[i].z * kv.z + qv[i].w * kv.w;
        }
    }
    #pragma unroll
    for (int i = 0; i < 3; ++i) {
        #pragma unroll
        for (int j = 0; j < 4; ++j)
            sP[(3 * ty + i) * STRIDE + tx + 16 * j] = __expf(acc[i][j] * SCALE);
    }
    __syncthreads();

    // ---- PV phase: thread (uy,dx): u = 3uy+i (i<3) x d = 4dx..4dx+3 ----
    int dx = tid & 15, uy = tid >> 4;
    float o[3][4];
    float ls[3];
    #pragma unroll
    for (int i = 0; i < 3; ++i) {
        ls[i] = 0.f;
        #pragma unroll
        for (int c = 0; c < 4; ++c) o[i][c] = 0.f;
    }
    #pragma unroll 4
    for (int k4 = 0; k4 < 16; ++k4) {
        float pa[3][4];
        #pragma unroll
        for (int i = 0; i < 3; ++i)
            *(float4*)pa[i] = *(const float4*)(sP + (3 * uy + i) * STRIDE + 4 * k4);
        #pragma unroll
        for (int c = 0; c < 4; ++c) {
            float4 vr = *(const float4*)(sV + (4 * k4 + c) * STRIDE + 4 * dx);
            #pragma unroll
            for (int i = 0; i < 3; ++i) {
                o[i][0] += pa[i][c] * vr.x;
                o[i][1] += pa[i][c] * vr.y;
                o[i][2] += pa[i][c] * vr.z;
                o[i][3] += pa[i][c] * vr.w;
                ls[i]   += pa[i][c];
            }
        }
    }
    // store partials (contention-free)
    #pragma unroll
    for (int i = 0; i < 3; ++i) {
        int u = 3 * uy + i;
        if (u < NTOP_) {
            long base = ((long)(split * 16 + bh) * NTOP_ + u) * D_;
            *(float4*)(pOut + base + 4 * dx) = make_float4(o[i][0], o[i][1], o[i][2], o[i][3]);
            if (dx == 0) plPart[(long)(split * 16 + bh) * NTOP_ + u] = ls[i];
        }
    }
}

// ---------------- K4: reduce partials across splits, normalize, scatter ----------------
__global__ __launch_bounds__(256) void reduce_norm_kernel(
    const int* __restrict__ topIdx, const float* __restrict__ pOut,
    const float* __restrict__ plPart, float* __restrict__ out, int nsplit) {
    __shared__ float part[4][64];
    __shared__ float lpart[4];
    int u = blockIdx.x, bh = blockIdx.y;
    int b = bh >> 3, h = bh & 7;
    int tid = threadIdx.x;
    int d = tid & 63, sg = tid >> 6;
    float acc = 0.f, lsum = 0.f;
    for (int s = sg; s < nsplit; s += 4) {
        acc  += pOut[((long)(s * 16 + bh) * NTOP_ + u) * D_ + d];
        lsum += plPart[(long)(s * 16 + bh) * NTOP_ + u];
    }
    part[sg][d] = acc;
    if (d == 0) lpart[sg] = lsum;
    __syncthreads();
    if (sg == 0) {
        float a = part[0][d] + part[1][d] + part[2][d] + part[3][d];
        float lt = lpart[0] + lpart[1] + lpart[2] + lpart[3];
        int lq = topIdx[bh * NTOP_ + u];
        out[(((long)(b * L_ + lq)) * H_ + h) * D_ + d] = a / lt;
    }
}

extern "C" void kernel_launch(void* const* d_in, const int* in_sizes, int n_in,
                              void* d_out, int out_size, void* d_ws, size_t ws_size,
                              hipStream_t stream) {
    const float* q = (const float*)d_in[0];
    const float* k = (const float*)d_in[1];
    const float* v = (const float*)d_in[2];
    // d_in[3] = attn_mask (unused)
    const int* samp = (const int*)d_in[4];
    float* out = (float*)d_out;

    char* ws = (char*)d_ws;
    const size_t mBytes   = (size_t)B_ * H_ * L_ * sizeof(float);   // 512 KB
    const size_t topBytes = (size_t)B_ * H_ * NTOP_ * sizeof(int);  // 2880 B
    const size_t plBytes  = (size_t)NSPLIT * 16 * NTOP_ * sizeof(float);
    float* M      = (float*)ws;
    int*   topIdx = (int*)(ws + mBytes);
    float* plPart = (float*)(ws + mBytes + topBytes);
    float* pOut   = (float*)(ws + mBytes + topBytes + plBytes);

    // pick split count that fits the workspace
    int nsplit = NSPLIT;
    while (nsplit > 1) {
        size_t need = mBytes + topBytes + plBytes +
                      (size_t)nsplit * 16 * NTOP_ * D_ * sizeof(float);
        if (need <= ws_size) break;
        nsplit >>= 1;
    }

    hipMemsetAsync(d_out, 0, (size_t)out_size * sizeof(float), stream);

    compute_M_kernel<<<2048, 256, 0, stream>>>(q, k, samp, M);

    topk_kernel<<<B_ * H_, 256, 0, stream>>>(M, topIdx);

    attn_strip_kernel<<<nsplit * B_ * H_, 256, 0, stream>>>(
        q, k, v, topIdx, pOut, plPart, nsplit);

    dim3 gn(NTOP_, B_ * H_);
    reduce_norm_kernel<<<gn, 256, 0, stream>>>(topIdx, pOut, plPart, out, nsplit);
}